// Round 14
// baseline (94.986 us; speedup 1.0000x reference)
//
#include <hip/hip_runtime.h>

// Problem constants (reference: B=8, N=4096, F=1024, C=64)
#define B_   8
#define N_   4096
#define F_   1024
#define C_   64
#define ROWS 64          // rows per block (4 waves x 16 rows)
#define KC   32          // K (f) floats per chunk
#define NT   (F_ / KC)   // 32 chunks
#define NBLK (N_ / ROWS) // 64 row-blocks per (inp,b)
#define MARGIN 0.08f     // hi-only bf16 score error sigma ~6e-3; 0.08 ~ 10 sigma on diffs

typedef __attribute__((ext_vector_type(8))) short bhalf8;   // 8 bf16 (MFMA A/B frag)
typedef __attribute__((ext_vector_type(4))) float f32x4;    // MFMA C/D frag
typedef __attribute__((ext_vector_type(4))) unsigned short us4;

__device__ __forceinline__ unsigned short f2bf_rne(float x) {
    unsigned u = __builtin_bit_cast(unsigned, x);
    u += 0x7fffu + ((u >> 16) & 1u);          // round-to-nearest-even
    return (unsigned short)(u >> 16);
}
__device__ __forceinline__ bhalf8 cvt8(float4 a, float4 b) {
    bhalf8 r;
    r[0] = (short)f2bf_rne(a.x); r[1] = (short)f2bf_rne(a.y);
    r[2] = (short)f2bf_rne(a.z); r[3] = (short)f2bf_rne(a.w);
    r[4] = (short)f2bf_rne(b.x); r[5] = (short)f2bf_rne(b.y);
    r[6] = (short)f2bf_rne(b.z); r[7] = (short)f2bf_rne(b.w);
    return r;
}
// Direct global->LDS. LDS dest is wave-uniform base + lane*16; global src is
// per-lane (carries the bank pre-swizzle).
__device__ __forceinline__ void load_lds16(const void* g, void* l) {
    __builtin_amdgcn_global_load_lds(
        (const __attribute__((address_space(1))) unsigned int*)g,
        (__attribute__((address_space(3))) unsigned int*)l, 16, 0, 0);
}

#define LEXGT(a, ai, b, bi) ((a) > (b) || ((a) == (b) && (ai) < (bi)))
#define INSERT3(vv, nn)                                                        \
    do {                                                                       \
        float _v = (vv); int _n = (nn);                                        \
        if (LEXGT(_v, _n, v0, i0)) { v2=v1; i2=i1; v1=v0; i1=i0; v0=_v; i0=_n; } \
        else if (LEXGT(_v, _n, v1, i1)) { v2=v1; i2=i1; v1=_v; i1=_n; }        \
        else if (LEXGT(_v, _n, v2, i2)) { v2=_v; i2=_n; }                      \
    } while (0)

// K0: convert W (fp32 [64][1024]) to bf16 (hi only) in workspace.
__global__ __launch_bounds__(256) void wconv_kernel(
    const float* __restrict__ W, unsigned short* __restrict__ Wh)
{
    int i = blockIdx.x * 256 + threadIdx.x;        // 16384 float4s total
    float4 v = ((const float4*)W)[i];
    us4 hh;
    hh[0] = f2bf_rne(v.x); hh[1] = f2bf_rne(v.y);
    hh[2] = f2bf_rne(v.z); hh[3] = f2bf_rne(v.w);
    ((us4*)Wh)[i] = hh;
}

// K1: hi-only bf16 MFMA scores with PER-WAVE-PRIVATE pipelines: each wave
// double-buffers ITS OWN 16 X-rows (2 KB/chunk) and ITS OWN W-chunk copy
// (4 KB) via global_load_lds, waits on its own counted vmcnt(6), and runs
// ZERO barriers in the main loop (the first structure with no block-wide
// sync; all prior ~66us variants shared buffers + __syncthreads per chunk).
// Same-wave safety: the lgkmcnt wait before each MFMA completes chunk t's
// ds_reads before stage(t+1)'s LDS writes can land. W staged redundantly
// per wave (L2-resident, L2 is idle). 12 KB/wave x 4 = 48 KB -> 3 blocks/CU
// = 12 independent pipelines/CU, 72 KB in flight sustained.
__global__ __launch_bounds__(256, 3) void score_top_kernel(
    const float* __restrict__ x1, const float* __restrict__ x2,
    const unsigned short* __restrict__ Wh,
    float* __restrict__ pv, int* __restrict__ pi)
{
    __shared__ __align__(16) char lds[49152];   // per wave: X[2][2KB] @WB, W[2][4KB] @WB+4096

    const int tid  = threadIdx.x;
    const int nb   = blockIdx.x;   // 0..63 (64-row group)
    const int b    = blockIdx.y;   // 0..7
    const int inp  = blockIdx.z;   // 0..1
    const float* __restrict__ x = inp ? x2 : x1;
    const float* __restrict__ xbase = x + ((size_t)b * N_ + (size_t)nb * ROWS) * F_;

    const int lane = tid & 63;
    const int w    = tid >> 6;       // wave 0..3 = m-tile
    const int rsel = lane & 15;
    const int g    = lane >> 4;      // 0..3

    char* const WB = lds + w * 12288;            // this wave's private region

#define XBUF(buf) (WB + (buf) * 2048)
#define WBUF(buf) (WB + 4096 + (buf) * 4096)

// 6 gload_lds per stage: 2 X (16 rows x 128B) + 4 W (64 cls x 64B), private.
#define STAGE(t, buf)                                                          \
    do {                                                                       \
        const int f0_ = (t) * KC;                                              \
        _Pragma("unroll")                                                      \
        for (int j = 0; j < 2; ++j) {                                          \
            int lr = j * 8 + (lane >> 3);            /* local row 0..15 */     \
            int r  = w * 16 + lr;                                              \
            int cg = (lane & 7) ^ (lr & 7);                                    \
            load_lds16(xbase + (size_t)r * F_ + f0_ + cg * 4,                  \
                       XBUF(buf) + j * 1024);                                  \
        }                                                                      \
        _Pragma("unroll")                                                      \
        for (int j = 0; j < 4; ++j) {                                          \
            int cls = j * 16 + (lane >> 2);                                    \
            int cg  = (lane & 3) ^ ((cls >> 1) & 3);                           \
            load_lds16(Wh + (size_t)cls * F_ + f0_ + cg * 8,                   \
                       WBUF(buf) + j * 1024);                                  \
        }                                                                      \
        __builtin_amdgcn_sched_barrier(0);                                     \
    } while (0)

#define COMPUTE(buf)                                                           \
    do {                                                                       \
        const char* xb = XBUF(buf);                                            \
        const char* wb = WBUF(buf);                                            \
        float4 xlo = *(const float4*)(xb + rsel * 128 + (((2 * g)     ^ (rsel & 7)) * 16)); \
        float4 xhi = *(const float4*)(xb + rsel * 128 + (((2 * g + 1) ^ (rsel & 7)) * 16)); \
        bhalf8 ah = cvt8(xlo, xhi);                                            \
        _Pragma("unroll")                                                      \
        for (int nt = 0; nt < 4; ++nt) {                                       \
            int cls = nt * 16 + rsel;                                          \
            bhalf8 bf = *(const bhalf8*)(wb + cls * 64 + ((g ^ ((cls >> 1) & 3)) * 16)); \
            acc[nt] = __builtin_amdgcn_mfma_f32_16x16x32_bf16(ah, bf, acc[nt], 0, 0, 0); \
        }                                                                      \
        __builtin_amdgcn_sched_barrier(0);                                     \
    } while (0)

    f32x4 acc[4];
    #pragma unroll
    for (int nt = 0; nt < 4; ++nt) acc[nt] = (f32x4){0.f, 0.f, 0.f, 0.f};

    STAGE(0, 0);                                  // 6 outstanding

    for (int t = 0; t < NT - 1; ++t) {
        STAGE(t + 1, (t + 1) & 1);                // +6 -> 12 outstanding
        asm volatile("s_waitcnt vmcnt(6)" ::: "memory");   // chunk t landed
        __builtin_amdgcn_sched_barrier(0);
        COMPUTE(t & 1);
    }
    asm volatile("s_waitcnt vmcnt(0)" ::: "memory");
    __builtin_amdgcn_sched_barrier(0);
    COMPUTE((NT - 1) & 1);

    // ---- per-wave top-3 per class. D layout: col=rsel (class), row=4g+r.
    float wv0[4], wv1[4], wv2[4]; int wi0[4], wi1[4], wi2[4];
    #pragma unroll
    for (int nt = 0; nt < 4; ++nt) {
        float v0 = -3.4e38f, v1 = -3.4e38f, v2 = -3.4e38f;
        int   i0 = 0x7fffffff, i1 = 0x7fffffff, i2 = 0x7fffffff;
        #pragma unroll
        for (int r = 0; r < 4; ++r) {
            int n = nb * ROWS + w * 16 + 4 * g + r;
            INSERT3(acc[nt][r], n);
        }
        #pragma unroll
        for (int d = 16; d <= 32; d <<= 1) {
            float u0 = __shfl_xor(v0, d), u1 = __shfl_xor(v1, d), u2 = __shfl_xor(v2, d);
            int   j0 = __shfl_xor(i0, d), j1 = __shfl_xor(i1, d), j2 = __shfl_xor(i2, d);
            INSERT3(u0, j0); INSERT3(u1, j1); INSERT3(u2, j2);
        }
        wv0[nt] = v0; wv1[nt] = v1; wv2[nt] = v2;
        wi0[nt] = i0; wi1[nt] = i1; wi2[nt] = i2;
    }

    __syncthreads();                 // all waves done with private buffers -> alias
    float* tv = (float*)lds;                   // [4][64][3] = 3 KiB
    int*   ti = (int*)(lds + 8192);            // [4][64][3] = 3 KiB
    if (lane < 16) {
        #pragma unroll
        for (int nt = 0; nt < 4; ++nt) {
            int c = nt * 16 + lane;
            tv[(w * C_ + c) * 3 + 0] = wv0[nt]; ti[(w * C_ + c) * 3 + 0] = wi0[nt];
            tv[(w * C_ + c) * 3 + 1] = wv1[nt]; ti[(w * C_ + c) * 3 + 1] = wi1[nt];
            tv[(w * C_ + c) * 3 + 2] = wv2[nt]; ti[(w * C_ + c) * 3 + 2] = wi2[nt];
        }
    }
    __syncthreads();

    // ---- block top-3 per class over 4 waves x 3, write partials
    if (tid < C_) {
        int c = tid;
        float v0 = -3.4e38f, v1 = -3.4e38f, v2 = -3.4e38f;
        int   i0 = 0x7fffffff, i1 = 0x7fffffff, i2 = 0x7fffffff;
        #pragma unroll
        for (int ww = 0; ww < 4; ++ww)
            #pragma unroll
            for (int k = 0; k < 3; ++k)
                INSERT3(tv[(ww * C_ + c) * 3 + k], ti[(ww * C_ + c) * 3 + k]);
        int blk = ((inp * B_ + b) * NBLK + nb);
        pv[(blk * C_ + c) * 3 + 0] = v0; pi[(blk * C_ + c) * 3 + 0] = i0;
        pv[(blk * C_ + c) * 3 + 1] = v1; pi[(blk * C_ + c) * 3 + 1] = i1;
        pv[(blk * C_ + c) * 3 + 2] = v2; pi[(blk * C_ + c) * 3 + 2] = i2;
    }
}

// K2: ONE WAVE per (inp,b,c). lane = row-block (64), each holds its top-3.
// Ballot-collect candidates within MARGIN of global max; exact fp32 dot
// rescue if >1 (lex tie-break: score desc, index asc); gather winning row.
__global__ __launch_bounds__(64) void select_gather_kernel(
    const float* __restrict__ x1, const float* __restrict__ x2,
    const float* __restrict__ W,
    const float* __restrict__ pv, const int* __restrict__ pi,
    float* __restrict__ out)
{
    const int c    = blockIdx.x;    // 0..63
    const int b    = blockIdx.y;    // 0..7
    const int inp  = blockIdx.z;    // 0..1
    const int lane = threadIdx.x;   // 0..63 = row-block

    const int blk  = ((inp * B_ + b) * NBLK + lane);
    const int base = (blk * C_ + c) * 3;
    const float v0 = pv[base + 0], v1 = pv[base + 1], v2 = pv[base + 2];
    const int   j0 = pi[base + 0], j1 = pi[base + 1], j2 = pi[base + 2];

    float m = v0;                       // entries sorted: v0 is block max
    #pragma unroll
    for (int d = 32; d; d >>= 1) m = fmaxf(m, __shfl_xor(m, d));
    const float thr = m - MARGIN;

    int cand[8]; int nc = 0;
    #pragma unroll
    for (int k = 0; k < 3; ++k) {
        float vk = k == 0 ? v0 : (k == 1 ? v1 : v2);
        int   jk = k == 0 ? j0 : (k == 1 ? j1 : j2);
        unsigned long long mask = __ballot(vk >= thr);
        while (mask) {
            int l = __ffsll(mask) - 1; mask &= mask - 1;
            int n = __shfl(jk, l);
            if (nc < 8) cand[nc++] = n;
        }
    }

    const float* __restrict__ x = inp ? x2 : x1;
    int winner;
    if (nc == 1) {
        winner = cand[0];
    } else {
        float bv = -3.4e38f; int bn = 0x7fffffff;
        const float4* wrow = (const float4*)(W + (size_t)c * F_) + lane * 4;
        for (int k = 0; k < nc; ++k) {
            int n = cand[k];
            const float4* xrow = (const float4*)(x + ((size_t)b * N_ + n) * F_) + lane * 4;
            float p = 0.f;
            #pragma unroll
            for (int q = 0; q < 4; ++q) {
                float4 xv = xrow[q], wq = wrow[q];
                p += xv.x * wq.x + xv.y * wq.y + xv.z * wq.z + xv.w * wq.w;
            }
            #pragma unroll
            for (int d = 32; d; d >>= 1) p += __shfl_xor(p, d);   // all lanes get sum
            if (p > bv || (p == bv && n < bn)) { bv = p; bn = n; }
        }
        winner = bn;
    }

    const float4* src = (const float4*)(x + ((size_t)b * N_ + winner) * F_);
    float4* dst = (float4*)(out + (((size_t)inp * B_ + b) * C_ + c) * F_);
    #pragma unroll
    for (int q = 0; q < 4; ++q) dst[lane + 64 * q] = src[lane + 64 * q];
}

extern "C" void kernel_launch(void* const* d_in, const int* in_sizes, int n_in,
                              void* d_out, int out_size, void* d_ws, size_t ws_size,
                              hipStream_t stream) {
    const float* x1 = (const float*)d_in[0];
    const float* x2 = (const float*)d_in[1];
    const float* W  = (const float*)d_in[2];
    // d_in[3] (bias) is constant per class -> cannot change the argmax. Skipped.

    // ws: Wh bf16 [64][1024] = 128 KiB | pv [1024][64][3] f32 = 768 KiB | pi = 768 KiB
    unsigned short* Wh = (unsigned short*)d_ws;
    float* pv = (float*)((char*)d_ws + (size_t)C_ * F_ * sizeof(unsigned short));
    int*   pi = (int*)((char*)pv + (size_t)2 * B_ * NBLK * C_ * 3 * sizeof(float));

    wconv_kernel<<<C_ * F_ / 1024, 256, 0, stream>>>(W, Wh);
    dim3 g1(NBLK, B_, 2);
    score_top_kernel<<<g1, 256, 0, stream>>>(x1, x2, Wh, pv, pi);
    dim3 g2(C_, B_, 2);
    select_gather_kernel<<<g2, 64, 0, stream>>>(x1, x2, W, pv, pi, (float*)d_out);
}

// Round 15
// 63.908 us; speedup vs baseline: 1.4863x; 1.4863x over previous
//
#include <hip/hip_runtime.h>

// Problem constants (reference: B=8, N=4096, F=1024, C=64)
#define B_   8
#define N_   4096
#define F_   1024
#define C_   64
#define ROWS 32          // rows per block
#define KC   64          // K (f) floats per chunk -> 256 B contiguous per row visit
#define NT   (F_ / KC)   // 16 chunks
#define NBLK (N_ / ROWS) // 128 row-blocks per (inp,b)
#define MARGIN 0.08f     // hi-only bf16 score error sigma ~6e-3; 0.08 ~ 10 sigma on diffs

typedef __attribute__((ext_vector_type(8))) short bhalf8;   // 8 bf16 (MFMA A/B frag)
typedef __attribute__((ext_vector_type(4))) float f32x4;    // MFMA C/D frag
typedef __attribute__((ext_vector_type(4))) unsigned short us4;

__device__ __forceinline__ unsigned short f2bf_rne(float x) {
    unsigned u = __builtin_bit_cast(unsigned, x);
    u += 0x7fffu + ((u >> 16) & 1u);          // round-to-nearest-even
    return (unsigned short)(u >> 16);
}
__device__ __forceinline__ bhalf8 cvt8(float4 a, float4 b) {
    bhalf8 r;
    r[0] = (short)f2bf_rne(a.x); r[1] = (short)f2bf_rne(a.y);
    r[2] = (short)f2bf_rne(a.z); r[3] = (short)f2bf_rne(a.w);
    r[4] = (short)f2bf_rne(b.x); r[5] = (short)f2bf_rne(b.y);
    r[6] = (short)f2bf_rne(b.z); r[7] = (short)f2bf_rne(b.w);
    return r;
}
// Direct global->LDS. LDS dest is wave-uniform base + lane*16; global src is
// per-lane (carries the bank pre-swizzle, permuting 16B granules WITHIN the
// row's 256B chunk so the DRAM footprint stays one contiguous 256B segment).
__device__ __forceinline__ void load_lds16(const void* g, void* l) {
    __builtin_amdgcn_global_load_lds(
        (const __attribute__((address_space(1))) unsigned int*)g,
        (__attribute__((address_space(3))) unsigned int*)l, 16, 0, 0);
}

#define LEXGT(a, ai, b, bi) ((a) > (b) || ((a) == (b) && (ai) < (bi)))
#define INSERT2(vv, nn)                                                        \
    do {                                                                       \
        float _v = (vv); int _n = (nn);                                        \
        if (LEXGT(_v, _n, v0, i0)) { v1=v0; i1=i0; v0=_v; i0=_n; }             \
        else if (LEXGT(_v, _n, v1, i1)) { v1=_v; i1=_n; }                      \
    } while (0)

// K0: convert W (fp32 [64][1024]) to bf16 (hi only) in workspace.
__global__ __launch_bounds__(256) void wconv_kernel(
    const float* __restrict__ W, unsigned short* __restrict__ Wh)
{
    int i = blockIdx.x * 256 + threadIdx.x;        // 16384 float4s total
    float4 v = ((const float4*)W)[i];
    us4 hh;
    hh[0] = f2bf_rne(v.x); hh[1] = f2bf_rne(v.y);
    hh[2] = f2bf_rne(v.z); hh[3] = f2bf_rne(v.w);
    ((us4*)Wh)[i] = hh;
}

// K1: hi-only bf16 MFMA scores. R7 2-phase global_load_lds pipeline with
// 2x DRAM page locality: KC=64 -> each X stage instruction reads 4 rows x
// 256 B CONTIGUOUS (vs 8 rows x 128 B before); page visits per row halve.
// 256 thr = 4 waves (wm = w&1: 16 rows; wn = w>>1: 32 classes), ROWS=32,
// 32 KiB LDS -> 5 blocks/CU. Per-block k-chunk stagger kept (free).
__global__ __launch_bounds__(256, 5) void score_top_kernel(
    const float* __restrict__ x1, const float* __restrict__ x2,
    const unsigned short* __restrict__ Wh,
    float* __restrict__ pv, int* __restrict__ pi)
{
    __shared__ __align__(16) char lds[32768];   // X: [2][32][256B] @0; W: [2][64][128B] @16384

    const int tid  = threadIdx.x;
    const int nb   = blockIdx.x;   // 0..127 (32-row group)
    const int b    = blockIdx.y;   // 0..7
    const int inp  = blockIdx.z;   // 0..1
    const float* __restrict__ x = inp ? x2 : x1;
    const char* __restrict__ xbase = (const char*)(x + ((size_t)b * N_ + (size_t)nb * ROWS) * F_);
    const char* __restrict__ wbase = (const char*)Wh;

    const int lane = tid & 63;
    const int w    = tid >> 6;       // wave 0..3
    const int wm   = w & 1;          // m-tile (16 rows)
    const int wn   = w >> 1;         // n-half (32 classes)
    const int rsel = lane & 15;
    const int g    = lane >> 4;      // 0..3

    const int t0 = (nb ^ (b << 2) ^ (inp << 3)) & (NT - 1);   // chunk stagger

#define XOFF(buf) ((buf) * 8192)
#define WOFF(buf) (16384 + (buf) * 8192)

#define STAGE(t, buf)                                                          \
    do {                                                                       \
        const int tb = (t);                                                    \
        _Pragma("unroll")                                                      \
        for (int j = 0; j < 2; ++j) {        /* X: 4 rows x 256B per inst */   \
            int rb = w * 8 + j * 4;                                            \
            int r  = rb + (lane >> 4);                                         \
            int off = ((lane & 15) * 16) ^ ((r & 7) << 4);                     \
            load_lds16(xbase + (size_t)r * 4096 + tb * 256 + off,              \
                       lds + XOFF(buf) + rb * 256);                            \
        }                                                                      \
        _Pragma("unroll")                                                      \
        for (int j = 0; j < 2; ++j) {        /* W: 8 cls x 128B per inst */    \
            int ib  = w * 2 + j;                                               \
            int cls = ib * 8 + (lane >> 3);                                    \
            int off = ((lane & 7) * 16) ^ ((cls & 7) << 4);                    \
            load_lds16(wbase + (size_t)cls * 2048 + tb * 128 + off,            \
                       lds + WOFF(buf) + ib * 1024);                           \
        }                                                                      \
    } while (0)

#define COMPUTE(buf)                                                           \
    do {                                                                       \
        const char* xb = lds + XOFF(buf);                                      \
        const char* wb = lds + WOFF(buf);                                      \
        _Pragma("unroll")                                                      \
        for (int ks = 0; ks < 2; ++ks) {                                       \
            float4 xlo = *(const float4*)(xb + row_ * 256 + ((ks * 128 + g * 32)      ^ aswz)); \
            float4 xhi = *(const float4*)(xb + row_ * 256 + ((ks * 128 + g * 32 + 16) ^ aswz)); \
            bhalf8 ah = cvt8(xlo, xhi);                                        \
            _Pragma("unroll")                                                  \
            for (int ntl = 0; ntl < 2; ++ntl) {                                \
                int cls = wn * 32 + ntl * 16 + rsel;                           \
                bhalf8 bf = *(const bhalf8*)(wb + cls * 128 + ((ks * 64 + g * 16) ^ aswz)); \
                acc[ntl] = __builtin_amdgcn_mfma_f32_16x16x32_bf16(ah, bf, acc[ntl], 0, 0, 0); \
            }                                                                  \
        }                                                                      \
    } while (0)

    f32x4 acc[2];
    acc[0] = (f32x4){0.f, 0.f, 0.f, 0.f};
    acc[1] = (f32x4){0.f, 0.f, 0.f, 0.f};

    const int row_ = wm * 16 + rsel;          // local A row (0..31)
    const int aswz = (rsel & 7) << 4;         // row&7 == cls&7 == rsel&7

    STAGE(t0, 0);
    __syncthreads();

    for (int t = 0; t < NT; ++t) {
        const int cur = t & 1;
        if (t + 1 < NT) STAGE((t0 + t + 1) & (NT - 1), cur ^ 1);
        COMPUTE(cur);
        __syncthreads();   // drains STAGE vmcnt; protects buffer reuse
    }

    // ---- per-wave top-2 per class. D layout: col=rsel (class), row=4g+r.
    float wv0[2], wv1[2]; int wi0[2], wi1[2];
    #pragma unroll
    for (int ntl = 0; ntl < 2; ++ntl) {
        float v0 = -3.4e38f, v1 = -3.4e38f;
        int   i0 = 0x7fffffff, i1 = 0x7fffffff;
        #pragma unroll
        for (int r = 0; r < 4; ++r) {
            int n = nb * ROWS + wm * 16 + 4 * g + r;
            INSERT2(acc[ntl][r], n);
        }
        #pragma unroll
        for (int d = 16; d <= 32; d <<= 1) {
            float u0 = __shfl_xor(v0, d), u1 = __shfl_xor(v1, d);
            int   j0 = __shfl_xor(i0, d), j1 = __shfl_xor(i1, d);
            INSERT2(u0, j0); INSERT2(u1, j1);
        }
        wv0[ntl] = v0; wv1[ntl] = v1;
        wi0[ntl] = i0; wi1[ntl] = i1;
    }

    __syncthreads();                 // done with X/W buffers -> safe to alias
    float* tv = (float*)lds;                   // [2 wm][64][2] = 1 KiB
    int*   ti = (int*)(lds + 4096);            // [2 wm][64][2] = 1 KiB
    if (lane < 16) {
        #pragma unroll
        for (int ntl = 0; ntl < 2; ++ntl) {
            int c = wn * 32 + ntl * 16 + lane;
            tv[(wm * C_ + c) * 2 + 0] = wv0[ntl]; ti[(wm * C_ + c) * 2 + 0] = wi0[ntl];
            tv[(wm * C_ + c) * 2 + 1] = wv1[ntl]; ti[(wm * C_ + c) * 2 + 1] = wi1[ntl];
        }
    }
    __syncthreads();

    // ---- block top-2 per class over 2 wm-waves x 2, write partials
    if (tid < C_) {
        int c = tid;
        float v0 = -3.4e38f, v1 = -3.4e38f;
        int   i0 = 0x7fffffff, i1 = 0x7fffffff;
        #pragma unroll
        for (int ww = 0; ww < 2; ++ww)
            #pragma unroll
            for (int k = 0; k < 2; ++k)
                INSERT2(tv[(ww * C_ + c) * 2 + k], ti[(ww * C_ + c) * 2 + k]);
        int blk = ((inp * B_ + b) * NBLK + nb);
        pv[(blk * C_ + c) * 2 + 0] = v0; pi[(blk * C_ + c) * 2 + 0] = i0;
        pv[(blk * C_ + c) * 2 + 1] = v1; pi[(blk * C_ + c) * 2 + 1] = i1;
    }
}

// K2: ONE WAVE per (inp,b,c). 256 entries (128 blocks x top-2) = 4 per lane.
// Ballot-collect candidates within MARGIN of global max; exact fp32 dot
// rescue if >1 (lex tie-break: score desc, index asc); gather winning row.
__global__ __launch_bounds__(64) void select_gather_kernel(
    const float* __restrict__ x1, const float* __restrict__ x2,
    const float* __restrict__ W,
    const float* __restrict__ pv, const int* __restrict__ pi,
    float* __restrict__ out)
{
    const int c    = blockIdx.x;    // 0..63
    const int b    = blockIdx.y;    // 0..7
    const int inp  = blockIdx.z;    // 0..1
    const int lane = threadIdx.x;   // 0..63; handles blocks 2*lane, 2*lane+1

    float v[4]; int id[4];
    #pragma unroll
    for (int j = 0; j < 2; ++j) {
        int blk = ((inp * B_ + b) * NBLK + lane * 2 + j);
        #pragma unroll
        for (int k = 0; k < 2; ++k) {
            int off = (blk * C_ + c) * 2 + k;
            v[j * 2 + k] = pv[off]; id[j * 2 + k] = pi[off];
        }
    }

    float m = fmaxf(fmaxf(v[0], v[1]), fmaxf(v[2], v[3]));
    #pragma unroll
    for (int d = 32; d; d >>= 1) m = fmaxf(m, __shfl_xor(m, d));
    const float thr = m - MARGIN;

    int cand[8]; int nc = 0;
    #pragma unroll
    for (int k = 0; k < 4; ++k) {
        unsigned long long mask = __ballot(v[k] >= thr);
        while (mask) {
            int l = __ffsll(mask) - 1; mask &= mask - 1;
            int n = __shfl(id[k], l);
            if (nc < 8) cand[nc++] = n;
        }
    }

    const float* __restrict__ x = inp ? x2 : x1;
    int winner;
    if (nc == 1) {
        winner = cand[0];
    } else {
        float bv = -3.4e38f; int bn = 0x7fffffff;
        const float4* wrow = (const float4*)(W + (size_t)c * F_) + lane * 4;
        for (int k = 0; k < nc; ++k) {
            int n = cand[k];
            const float4* xrow = (const float4*)(x + ((size_t)b * N_ + n) * F_) + lane * 4;
            float p = 0.f;
            #pragma unroll
            for (int q = 0; q < 4; ++q) {
                float4 xv = xrow[q], wq = wrow[q];
                p += xv.x * wq.x + xv.y * wq.y + xv.z * wq.z + xv.w * wq.w;
            }
            #pragma unroll
            for (int d = 32; d; d >>= 1) p += __shfl_xor(p, d);   // all lanes get sum
            if (p > bv || (p == bv && n < bn)) { bv = p; bn = n; }
        }
        winner = bn;
    }

    const float4* src = (const float4*)(x + ((size_t)b * N_ + winner) * F_);
    float4* dst = (float4*)(out + (((size_t)inp * B_ + b) * C_ + c) * F_);
    #pragma unroll
    for (int q = 0; q < 4; ++q) dst[lane + 64 * q] = src[lane + 64 * q];
}

extern "C" void kernel_launch(void* const* d_in, const int* in_sizes, int n_in,
                              void* d_out, int out_size, void* d_ws, size_t ws_size,
                              hipStream_t stream) {
    const float* x1 = (const float*)d_in[0];
    const float* x2 = (const float*)d_in[1];
    const float* W  = (const float*)d_in[2];
    // d_in[3] (bias) is constant per class -> cannot change the argmax. Skipped.

    // ws: Wh bf16 [64][1024] = 128 KiB | pv [2048][64][2] f32 = 1 MiB | pi = 1 MiB
    unsigned short* Wh = (unsigned short*)d_ws;
    float* pv = (float*)((char*)d_ws + (size_t)C_ * F_ * sizeof(unsigned short));
    int*   pi = (int*)((char*)pv + (size_t)2 * B_ * NBLK * C_ * 2 * sizeof(float));

    wconv_kernel<<<C_ * F_ / 1024, 256, 0, stream>>>(W, Wh);
    dim3 g1(NBLK, B_, 2);
    score_top_kernel<<<g1, 256, 0, stream>>>(x1, x2, Wh, pv, pi);
    dim3 g2(C_, B_, 2);
    select_gather_kernel<<<g2, 64, 0, stream>>>(x1, x2, W, pv, pi, (float*)d_out);
}